// Round 1
// baseline (1328.404 us; speedup 1.0000x reference)
//
#include <hip/hip_runtime.h>

// Problem constants (fixed by the reference: B=4, MAX_LEN=4096, H=32, D=128, Q_LEN=1)
constexpr long long N_ELEM  = 4LL * 4096 * 32 * 128; // 67,108,864 per K or V tensor
constexpr long long N_ROWS  = 4LL * 4096 * 32;       // 524,288 rows of D=128
constexpr long long MASK_N  = 4LL * 4096;            // 16,384
constexpr long long SCALE_N = N_ROWS;                // 524,288

// d_out float32 layout (flat, return order):
//   [0, N)                  key_out
//   [N, 2N)                 value_out
//   [2N, 2N+MASK)           attn_mask_out (bool as 0.0/1.0)
//   [2N+MASK, 3N+MASK)      key_q (int8 value as float)
//   [3N+MASK, +SCALE)       key_scale
//   [.., +N)                value_q
//   [.., +SCALE)            value_scale

__global__ __launch_bounds__(256) void kv_update_quant_kernel(
    const float* __restrict__ cached_key,
    const float* __restrict__ cached_value,
    const float* __restrict__ key_new,     // (B,1,H,D)
    const float* __restrict__ value_new,   // (B,1,H,D)
    const int*   __restrict__ cache_index,
    float* __restrict__ out)
{
    const int cur = cache_index[0];

    // 8 rows per 256-thread block: one row per half-wave (32 lanes x float4 = 128 floats)
    const long long row  = (long long)blockIdx.x * 8 + (threadIdx.x >> 5);
    const int lane = threadIdx.x & 31;
    const bool isv = row >= N_ROWS;               // value-tensor half of the row space
    const long long r = isv ? row - N_ROWS : row; // row within tensor: r = (b*4096+s)*32+h

    const int h = (int)(r & 31);
    const int s = (int)((r >> 5) & 4095);
    const long long b = r >> 17;

    // dynamic_update_slice: row at s == cache_index comes from the new K/V
    const float* src;
    if (s == cur) {
        src = (isv ? value_new : key_new) + (((b << 5) + (long long)h) << 7);
    } else {
        src = (isv ? cached_value : cached_key) + (r << 7);
    }
    const float4 v = reinterpret_cast<const float4*>(src)[lane];

    // max |x| over the 128-row: 4 local, then 5-step xor-shuffle across the half-wave.
    // xor masks <= 16 keep lanes 0-31 and 32-63 reducing independently.
    float m = fmaxf(fmaxf(fabsf(v.x), fabsf(v.y)), fmaxf(fabsf(v.z), fabsf(v.w)));
    #pragma unroll
    for (int off = 16; off >= 1; off >>= 1)
        m = fmaxf(m, __shfl_xor(m, off));

    // scale = max(|x|)/127, clamped; IEEE f32 div + rintf (round-half-even) matches
    // jnp round/div bitwise, so quant outputs are exact vs the numpy reference.
    const float scale = fmaxf(m / 127.0f, 1e-8f);

    float4 q;
    q.x = fminf(fmaxf(rintf(v.x / scale), -128.0f), 127.0f);
    q.y = fminf(fmaxf(rintf(v.y / scale), -128.0f), 127.0f);
    q.z = fminf(fmaxf(rintf(v.z / scale), -128.0f), 127.0f);
    q.w = fminf(fmaxf(rintf(v.w / scale), -128.0f), 127.0f);

    const long long elem_off = (r << 7) + ((long long)lane << 2);
    const long long out_off  = (isv ? N_ELEM : 0) + elem_off;
    const long long q_off    = 2 * N_ELEM + MASK_N + (isv ? (N_ELEM + SCALE_N) : 0) + elem_off;
    const long long s_off    = 3 * N_ELEM + MASK_N + (isv ? (N_ELEM + SCALE_N) : 0) + r;

    *reinterpret_cast<float4*>(out + out_off) = v;  // key_out / value_out (copy-through)
    *reinterpret_cast<float4*>(out + q_off)   = q;  // int8 quant values as float
    if (lane == 0) out[s_off] = scale;              // per-(b,s,h) scale
}

__global__ __launch_bounds__(256) void mask_kernel(
    const int* __restrict__ attention_mask,   // bool input, harness passes integer
    const int* __restrict__ cache_index,
    float* __restrict__ out_mask)             // 16,384 floats at out + 2N
{
    const int i = blockIdx.x * 256 + threadIdx.x;
    if (i < (int)MASK_N) {
        const int pos = i & 4095;
        const bool pad = pos < (cache_index[0] + 1);   // arange(max_len) < cur + num_updated
        const bool am  = attention_mask[i] != 0;
        out_mask[i] = (pad && am) ? 1.0f : 0.0f;
    }
}

extern "C" void kernel_launch(void* const* d_in, const int* in_sizes, int n_in,
                              void* d_out, int out_size, void* d_ws, size_t ws_size,
                              hipStream_t stream) {
    const float* cached_key   = (const float*)d_in[0];
    const float* cached_value = (const float*)d_in[1];
    const float* key_new      = (const float*)d_in[2];
    const float* value_new    = (const float*)d_in[3];
    const int*   attn_mask    = (const int*)d_in[4];
    const int*   cache_index  = (const int*)d_in[5];
    float* out = (float*)d_out;

    // 2 tensors x 524,288 rows, 8 rows/block -> 131,072 blocks
    kv_update_quant_kernel<<<131072, 256, 0, stream>>>(
        cached_key, cached_value, key_new, value_new, cache_index, out);

    mask_kernel<<<(int)(MASK_N / 256), 256, 0, stream>>>(
        attn_mask, cache_index, out + 2 * N_ELEM);
}